// Round 1
// 224.262 us; speedup vs baseline: 1.0176x; 1.0176x over previous
//
#include <hip/hip_runtime.h>
#include <stdint.h>

// Problem constants (fixed by reference)
#define BB    16
#define NN    1000
#define DD    2048
#define KK    256
#define SIG   0.05f
#define INVN  (1.0f / 1000.0f)

#define T1      256
#define NBUCK   4096    // kernel0: 12-bit high-bits histogram of x
#define CANDCAP 1536    // per-b candidate capacity (M ~ 650-750 expected)
#define MARGIN  0.6f    // 2 * SIG * 6sigma; candidate-miss needs two ~6sigma
                        // draws in one row: P ~ 1e-8 over all 16k rows

#define HBUCK 1024      // kernel1: fine buckets, (u-U0)>>15 = 1/256 octave
#define CMAX2 512       // crossing-candidate capacity (C ~ 258 expected)
#define CITER 6         // ceil(CANDCAP / T1)

// ---------------- Kernel 0: per-b candidate pruning ------------------------
// One block per b (16 blocks total -- cost is noise). Finds the histogram
// bucket of the K-th largest x, sets theta = bucket_floor - MARGIN, and
// compacts {d : x[b,d] >= theta} in ascending-d order (so reversed candidate
// index == reversed d for tie-breaks). Outputs per-b: cand_d, cand_x, and
// params = {U0 = monotone(theta), M}.
__global__ __launch_bounds__(T1) void ptopk_prune(
    const float* __restrict__ x,
    uint16_t* __restrict__ cand_d,
    float* __restrict__ cand_x,
    uint2* __restrict__ params)
{
    __shared__ __align__(16) uint16_t sF[NBUCK + 8];
    __shared__ uint32_t sWS[4];
    __shared__ uint32_t sBstar;
    __shared__ float    sTheta;

    const int t    = threadIdx.x;
    const int lane = t & 63;
    const int w    = t >> 6;
    const int b    = blockIdx.x;

    uint32_t* sFw = (uint32_t*)sF;
    uint4 z; z.x = z.y = z.z = z.w = 0u;
    uint4* sF4 = (uint4*)sF;
    sF4[t]      = z;
    sF4[t + T1] = z;
    if (t == 0) sF4[2 * T1] = z;
    __syncthreads();

    const float4* xrow = (const float4*)(x + (size_t)b * DD);
    float4 xa = xrow[t], xb = xrow[t + T1];
    float v[8];
    v[0] = xa.x; v[1] = xa.y; v[2] = xa.z; v[3] = xa.w;
    v[4] = xb.x; v[5] = xb.y; v[6] = xb.z; v[7] = xb.w;

    #pragma unroll
    for (int i = 0; i < 8; ++i) {
        uint32_t ub = __float_as_uint(v[i]);
        uint32_t u  = ub ^ (uint32_t)(((int32_t)ub >> 31) | (int32_t)0x80000000);
        uint32_t bk = u >> 20;
        atomicAdd(&sFw[bk >> 1], 1u << ((bk & 1) << 4));
    }
    __syncthreads();

    // suffix scan over 4096 buckets, 16 buckets per thread (packed pair-sums)
    uint4 ca = ((const uint4*)sF)[2 * t];
    uint4 cb = ((const uint4*)sF)[2 * t + 1];
    uint32_t S = ca.x + ca.y + ca.z + ca.w + cb.x + cb.y + cb.z + cb.w;
    uint32_t csum = (S & 0xFFFFu) + (S >> 16);
    uint32_t s = csum;
    #pragma unroll
    for (int ofs = 1; ofs < 64; ofs <<= 1) {
        uint32_t o = __shfl_down(s, ofs, 64);
        s += (lane + ofs < 64) ? o : 0u;
    }
    if (lane == 0) sWS[w] = s;
    __syncthreads();
    uint32_t waveAbove = 0;
    #pragma unroll
    for (int i = 0; i < 4; ++i) waveAbove += (i > w) ? sWS[i] : 0u;
    const uint32_t above = waveAbove + (s - csum);

    if (above < KK && above + csum >= KK) {
        uint32_t h[16];
        h[0]  = ca.x & 0xFFFFu;  h[1]  = ca.x >> 16;
        h[2]  = ca.y & 0xFFFFu;  h[3]  = ca.y >> 16;
        h[4]  = ca.z & 0xFFFFu;  h[5]  = ca.z >> 16;
        h[6]  = ca.w & 0xFFFFu;  h[7]  = ca.w >> 16;
        h[8]  = cb.x & 0xFFFFu;  h[9]  = cb.x >> 16;
        h[10] = cb.y & 0xFFFFu;  h[11] = cb.y >> 16;
        h[12] = cb.z & 0xFFFFu;  h[13] = cb.z >> 16;
        h[14] = cb.w & 0xFFFFu;  h[15] = cb.w >> 16;
        uint32_t Fi = above;
        for (int i = 15; i >= 0; --i) {
            Fi += h[i];
            if (Fi >= KK) { sBstar = (uint32_t)(16 * t + i); break; }
        }
    }
    __syncthreads();

    if (t == 0) {
        // reconstruct the lower edge of the crossing bucket, then subtract
        // the safety margin. theta <= tau_b - MARGIN by construction.
        uint32_t ulo   = sBstar << 20;
        uint32_t xbits = (ulo & 0x80000000u) ? (ulo - 0x80000000u) : ~ulo;
        sTheta = __uint_as_float(xbits) - MARGIN;
    }
    __syncthreads();
    const float theta = sTheta;

    // ordered compaction: half A (d = 4t+i), then half B (d = 1024+4t+i)
    uint32_t base = 0;
    #pragma unroll
    for (int half = 0; half < 2; ++half) {
        uint32_t cnt = 0;
        #pragma unroll
        for (int i = 0; i < 4; ++i) cnt += (v[4 * half + i] >= theta) ? 1u : 0u;
        uint32_t inc = cnt;
        #pragma unroll
        for (int ofs = 1; ofs < 64; ofs <<= 1) {
            uint32_t o = __shfl_up(inc, ofs, 64);
            inc += (lane >= ofs) ? o : 0u;
        }
        if (lane == 63) sWS[w] = inc;
        __syncthreads();
        uint32_t wbase = 0;
        #pragma unroll
        for (int i = 0; i < 4; ++i) wbase += (i < w) ? sWS[i] : 0u;
        uint32_t off = base + wbase + inc - cnt;
        #pragma unroll
        for (int i = 0; i < 4; ++i) {
            if (v[4 * half + i] >= theta) {
                if (off < CANDCAP) {
                    cand_d[(size_t)b * CANDCAP + off] =
                        (uint16_t)(1024 * half + 4 * t + i);
                    cand_x[(size_t)b * CANDCAP + off] = v[4 * half + i];
                }
                off++;
            }
        }
        base += sWS[0] + sWS[1] + sWS[2] + sWS[3];
        __syncthreads();     // protect sWS before half B rewrites it
    }

    if (t == 0) {
        uint32_t tb = __float_as_uint(theta);
        uint32_t U0 = tb ^ (uint32_t)(((int32_t)tb >> 31) | (int32_t)0x80000000);
        uint32_t M  = base;
        if (M > CANDCAP) M = CANDCAP;
        params[b] = make_uint2(U0, M);
    }
}

// ---------------- Kernel 1: per-row exact top-K ranks over candidates ------
// One block = one (b,n) row. Only the ~650 pruned candidates are processed:
// gather noise at candidate d's (d-ascending => line-coalesced), key into
// 1024 fine buckets of 2^15 u-units (~1/256 octave => crossing bucket holds
// ~1-2 elems, C ~ 258), packed suffix scan (4 buckets/thread), cursor
// compaction, exact within-bucket rank, direct scatter of ranks to idxT.
// LDS 8.2 KB (was 17.4), atomics ~650/row (was 2048), scan 4x smaller.
__global__ __launch_bounds__(T1, 8) void ptopk_rank(
    const float* __restrict__ noise,
    const uint16_t* __restrict__ cand_d,
    const float* __restrict__ cand_x,
    const uint2* __restrict__ params,
    uint16_t* __restrict__ idxT)
{
    __shared__ __align__(16) uint32_t sH[HBUCK / 2 + 4];  // 516 words: hist -> F -> cursors
    __shared__ __align__(16) uint32_t sCand[CMAX2];
    __shared__ __align__(16) uint16_t sCandBk[CMAX2];
    __shared__ __align__(16) uint16_t sCdd[CANDCAP];
    __shared__ uint32_t sWS[4];
    __shared__ uint32_t sBstar;

    const int t    = threadIdx.x;
    const int lane = t & 63;
    const int w    = t >> 6;
    // XCD swizzle: consecutive n on one XCD -> idxT cachelines produced by
    // a single L2 (kept from R7).
    const int row  = (blockIdx.x & 7) * (BB * NN / 8) + (blockIdx.x >> 3);
    const int b    = row / NN;
    const int n    = row - b * NN;

    const uint2 pp   = params[b];
    const uint32_t U0 = pp.x;
    const int M       = (int)pp.y;

    // zero hist (516 words) + stage candidate d-list (M uint16, <=192 uint4)
    ((uint2*)sH)[t] = make_uint2(0u, 0u);
    if (t < 4) sH[2 * T1 + t] = 0u;
    const uint4* gcd = (const uint4*)(cand_d + (size_t)b * CANDCAP);
    if (t < ((M + 7) >> 3)) ((uint4*)sCdd)[t] = gcd[t];
    __syncthreads();

    const float* nrow = noise + (size_t)row * DD;
    const float* cxb  = cand_x + (size_t)b * CANDCAP;

    uint32_t rr[CITER];
    #pragma unroll
    for (int i = 0; i < CITER; ++i) {
        rr[i] = 0u;
        const int j = t + i * T1;
        if (j < M) {
            const int d = (int)sCdd[j];
            // match numpy: separate rounded mul and add (no FMA contraction)
            const float vv = __fadd_rn(cxb[j], __fmul_rn(nrow[d], SIG));
            uint32_t ub = __float_as_uint(vv);
            uint32_t u  = ub ^ (uint32_t)(((int32_t)ub >> 31) | (int32_t)0x80000000);
            uint32_t r  = (u < U0) ? 0u : (u - U0);
            rr[i] = r;
            uint32_t bk = r >> 15;
            if (bk > HBUCK - 1) bk = HBUCK - 1;
            atomicAdd(&sH[bk >> 1], 1u << ((bk & 1) << 4));
        }
    }
    __syncthreads();

    // packed suffix scan: 4 buckets (1 uint2) per thread
    uint2 cw = ((const uint2*)sH)[t];
    uint32_t S = cw.x + cw.y;
    uint32_t csum = (S & 0xFFFFu) + (S >> 16);
    uint32_t s = csum;
    #pragma unroll
    for (int ofs = 1; ofs < 64; ofs <<= 1) {
        uint32_t o = __shfl_down(s, ofs, 64);
        s += (lane + ofs < 64) ? o : 0u;
    }
    if (lane == 0) sWS[w] = s;
    __syncthreads();
    uint32_t waveAbove = 0;
    #pragma unroll
    for (int i = 0; i < 4; ++i) waveAbove += (i > w) ? sWS[i] : 0u;
    const uint32_t above = waveAbove + (s - csum);   // F(4t+4)

    // exactly one thread's chunk contains the crossing
    if (above < KK && above + csum >= KK) {
        uint32_t h0 = cw.x & 0xFFFFu, h1 = cw.x >> 16;
        uint32_t h2 = cw.y & 0xFFFFu, h3 = cw.y >> 16;
        uint32_t Fi = above + h3;
        int bsel = 4 * t + 3;
        if (Fi < KK) { Fi += h2; bsel = 4 * t + 2; }
        if (Fi < KK) { Fi += h1; bsel = 4 * t + 1; }
        if (Fi < KK) { Fi += h0; bsel = 4 * t + 0; }
        sBstar = (uint32_t)bsel;
    }
    __syncthreads();
    const uint32_t bstar = sBstar;

    // publish F only for chunks covering buckets >= b*
    if (4 * t + 3 >= (int)bstar) {
        uint32_t h0 = cw.x & 0xFFFFu, h1 = cw.x >> 16;
        uint32_t h2 = cw.y & 0xFFFFu, h3 = cw.y >> 16;
        uint32_t F4 = above;
        uint32_t F3 = F4 + h3, F2 = F3 + h2, F1 = F2 + h1, F0 = F1 + h0;
        ((uint2*)sH)[t] = make_uint2(F0 | (F1 << 16), F2 | (F3 << 16));
    }
    __syncthreads();

    // compact candidates with bucket >= b* (cursor for bk is halfword bk+1;
    // halfword b* keeps F(b*) = C). key: within-bucket order = low 15 bits
    // of r; tie-break by reversed candidate index (== reversed d).
    #pragma unroll
    for (int i = 0; i < CITER; ++i) {
        const int j  = t + i * T1;
        uint32_t r   = rr[i];
        uint32_t bk  = r >> 15;
        if (bk > HBUCK - 1) bk = HBUCK - 1;
        if (j < M && bk >= bstar) {
            uint32_t ci  = bk + 1;
            uint32_t sh  = (ci & 1) << 4;
            uint32_t old = atomicAdd(&sH[ci >> 1], 1u << sh);
            uint32_t pos = (old >> sh) & 0xFFFFu;
            if (pos < CMAX2) {                    // safety guard (never hit)
                sCand[pos]   = ((r & 0x7FFFu) << 11) | (uint32_t)(2047 - j);
                sCandBk[pos] = (uint16_t)bk;
            }
        }
    }
    __syncthreads();

    // distributed rank loop; ranks scatter directly to global
    const uint16_t* sHh = (const uint16_t*)sH;
    int C = (int)sHh[bstar];                      // = F(b*)
    if (C > CMAX2) C = CMAX2;
    uint16_t* orow = idxT + (size_t)b * KK * NN + n;
    for (int p = t; p < C; p += T1) {
        const uint32_t key = sCand[p];
        const int bk       = (int)sCandBk[p];
        const uint32_t hi  = sHh[bk + 1];         // F(bk) after compaction
        const uint32_t lo  = sHh[bk + 2];         // F(bk+1)
        uint32_t rank = lo;
        for (uint32_t q = lo; q < hi; ++q)
            rank += (sCand[q] > key) ? 1u : 0u;
        if (rank < KK)
            orow[(size_t)rank * NN] = sCdd[2047 - (int)(key & 0x7FFu)];
    }
}

// ---------------- Kernel 2: accumulate indicators, dense write, no atomics --
// (unchanged from the 226.8us session kernel)
#define T2 64
__global__ __launch_bounds__(T2) void ptopk_accum(
    const uint16_t* __restrict__ idxT,
    float* __restrict__ out)
{
    __shared__ __align__(16) uint32_t hist[DD / 2];   // 1024 words = 256 uint4

    const int t   = threadIdx.x;
    const int bkx = blockIdx.x;          // = b*KK + k

    uint4 z; z.x = z.y = z.z = z.w = 0u;
    #pragma unroll
    for (int i = 0; i < 4; ++i)
        ((uint4*)hist)[i * T2 + t] = z;
    __syncthreads();

    const uint4* src = (const uint4*)(idxT + (size_t)bkx * NN);
    const bool hasA = (t <= 62);
    const bool hasB = (t <  62);
    if (hasA) {
        uint4 va = src[2 * t];
        uint16_t dv[16];
        dv[0] = (uint16_t)(va.x & 0xFFFFu); dv[1] = (uint16_t)(va.x >> 16);
        dv[2] = (uint16_t)(va.y & 0xFFFFu); dv[3] = (uint16_t)(va.y >> 16);
        dv[4] = (uint16_t)(va.z & 0xFFFFu); dv[5] = (uint16_t)(va.z >> 16);
        dv[6] = (uint16_t)(va.w & 0xFFFFu); dv[7] = (uint16_t)(va.w >> 16);
        uint32_t cur = dv[0], run = 1;
        #pragma unroll
        for (int i = 1; i < 8; ++i) {
            if (dv[i] == cur) { run++; }
            else {
                atomicAdd(&hist[cur >> 1], run << ((cur & 1) << 4));
                cur = dv[i]; run = 1;
            }
        }
        if (hasB) {
            uint4 vb = src[2 * t + 1];
            dv[8]  = (uint16_t)(vb.x & 0xFFFFu); dv[9]  = (uint16_t)(vb.x >> 16);
            dv[10] = (uint16_t)(vb.y & 0xFFFFu); dv[11] = (uint16_t)(vb.y >> 16);
            dv[12] = (uint16_t)(vb.z & 0xFFFFu); dv[13] = (uint16_t)(vb.z >> 16);
            dv[14] = (uint16_t)(vb.w & 0xFFFFu); dv[15] = (uint16_t)(vb.w >> 16);
            #pragma unroll
            for (int i = 8; i < 16; ++i) {
                if (dv[i] == cur) { run++; }
                else {
                    atomicAdd(&hist[cur >> 1], run << ((cur & 1) << 4));
                    cur = dv[i]; run = 1;
                }
            }
        }
        atomicAdd(&hist[cur >> 1], run << ((cur & 1) << 4));
    }
    __syncthreads();

    float4* out4 = (float4*)(out + (size_t)bkx * DD);
    #pragma unroll
    for (int i = 0; i < 4; ++i) {
        int j = i * T2 + t;
        uint4 wv = ((const uint4*)hist)[j];
        float4 f0, f1;
        f0.x = (float)(wv.x & 0xFFFFu) * INVN;  f0.y = (float)(wv.x >> 16) * INVN;
        f0.z = (float)(wv.y & 0xFFFFu) * INVN;  f0.w = (float)(wv.y >> 16) * INVN;
        f1.x = (float)(wv.z & 0xFFFFu) * INVN;  f1.y = (float)(wv.z >> 16) * INVN;
        f1.z = (float)(wv.w & 0xFFFFu) * INVN;  f1.w = (float)(wv.w >> 16) * INVN;
        out4[2 * j]     = f0;
        out4[2 * j + 1] = f1;
    }
}

extern "C" void kernel_launch(void* const* d_in, const int* in_sizes, int n_in,
                              void* d_out, int out_size, void* d_ws, size_t ws_size,
                              hipStream_t stream) {
    const float* x     = (const float*)d_in[0];
    const float* noise = (const float*)d_in[1];
    float* out         = (float*)d_out;

    // workspace layout:
    //   [0, 8192000)            idxT     : BB*KK*NN uint16 (transposed ranks)
    //   [8192000, 8241152)      cand_d   : BB*CANDCAP uint16
    //   [8241152, 8339456)      cand_x   : BB*CANDCAP float
    //   [8339456, 8339584)      params   : BB uint2 {U0, M}
    uint8_t* wsb      = (uint8_t*)d_ws;
    uint16_t* idxT    = (uint16_t*)wsb;
    uint16_t* cand_d  = (uint16_t*)(wsb + 8192000);
    float*    cand_x  = (float*)(wsb + 8241152);
    uint2*    params  = (uint2*)(wsb + 8339456);

    hipLaunchKernelGGL(ptopk_prune,
                       dim3(BB), dim3(T1), 0, stream,
                       x, cand_d, cand_x, params);
    hipLaunchKernelGGL(ptopk_rank,
                       dim3(BB * NN), dim3(T1), 0, stream,
                       noise, cand_d, cand_x, params, idxT);
    hipLaunchKernelGGL(ptopk_accum,
                       dim3(BB * KK), dim3(T2), 0, stream,
                       idxT, out);
}